// Round 8
// baseline (154.193 us; speedup 1.0000x reference)
//
#include <hip/hip_runtime.h>
#include <hip/hip_bf16.h>

// RadarSecondStageGenerator — MFMA fp16, round 17: r16 pipeline + pinned
// waves-per-EU. r16 post-mortem: FETCH/WRITE both +26MB = the 48 live
// B-tile floats spilled to scratch (compiler chose VGPR=64 chasing 8
// waves/EU that the 69KB LDS makes impossible; real cap is 2 blocks/CU =
// 4 waves/EU = 128 VGPR). amdgpu_waves_per_eu(4,4) pins the allocator to
// the true occupancy -> 128-reg budget -> no spill, B-tile loads stay in
// registers across tile-A compute (genuine latency hiding).
// Structure identical to r16:
//   * grid 512 x 512thr, block = two x-adjacent 32x16 tiles, two 34560B
//     staging pools (69KB -> 2 blocks/CU).
//   * tile-B global loads issued right after tile-A staging barrier,
//     packed/written to poolB after A's gates; conv_out(A) overlaps
//     conv_in(B). 7 barriers / 2 tiles.
//
// h0 == 0 ⇒ flow/warp/w_ret branch dead; network = conv3x3(24->8) ->
// conv3x3(8->24) -> GRU gates (h2h == b_ret) -> conv1x1(8->12).
// conv_in im2col: M = 612 x-halo px (39 tiles), N = 8, K-step = 4 taps x 8 ch.
// i2h: M = 512 px (32 tiles), N = 24 (2 N-tiles), K = 12 taps x 8 ch (3 steps).
// Fragment layouts (HW-verified): A[m=lane&15][k=quad*8+j], C[row=quad*4+reg][col=lane&15].

typedef __fp16   h2f __attribute__((ext_vector_type(2)));   // cvt_pkrtz return type
typedef _Float16 v8h __attribute__((ext_vector_type(8)));
typedef float    v4f __attribute__((ext_vector_type(4)));

#define HW 128
#define SPITCH 24        // halfs per staged position: 48 B, 16B-aligned, bank-clean
#define PCOLS 36         // staged patch: 36 cols x 20 rows
#define NPOS  720
#define SXW   34         // s_x grid 34 x 18
#define SXN   612
#define POOLB 34560      // one staging pool (bytes)

#define WB_HOFF 4608     // half-index of i2h B-frags in ws
#define FLT_OFF 16384    // byte offset of float params in ws
#define N_PREP  7828     // 4608 + 3072 halfs, then 148 floats

__global__ __launch_bounds__(256)
void prep(const float* __restrict__ w_in,  const float* __restrict__ b_in,
          const float* __restrict__ w_i2h, const float* __restrict__ b_i2h,
          const float* __restrict__ b_ret, const float* __restrict__ w_out,
          const float* __restrict__ b_out, void* __restrict__ ws)
{
    int idx = blockIdx.x * 256 + threadIdx.x;
    _Float16* wh = (_Float16*)ws;
    float* fw = (float*)((char*)ws + FLT_OFF);
    if (idx < 4608) {                       // conv_in B-frags [s3][g3][lane64][j8]
        int j = idx & 7, r = idx >> 3;
        int lane = r & 63, sg = r >> 6;     // sg = s*3 + g
        int g = sg % 3, s = sg / 3;
        int quad = lane >> 4, n = lane & 15;
        int tap = s * 4 + quad;             // 0..11 (9..11 zero pad)
        float v = (n < 8 && tap < 9) ? w_in[n*216 + (g*8 + j)*9 + tap] : 0.f;
        wh[idx] = (_Float16)v;
    } else if (idx < 7680) {                // i2h B-frags [s3][nt2][lane64][j8]
        int i2 = idx - 4608;
        int j = i2 & 7, r = i2 >> 3;
        int lane = r & 63; r >>= 6;
        int nt = r & 1, s = r >> 1;
        int quad = lane >> 4, n = lane & 15;
        int kk = s * 32 + quad * 8 + j;     // K: tap-major, 8 ch per tap
        int t = kk >> 3, m = kk & 7;        // tap 0..11 (9..11 pad)
        int o = nt * 16 + n;
        float v = (t < 9 && o < 24) ? w_i2h[o*72 + m*9 + t] : 0.f;
        wh[WB_HOFF + i2] = (_Float16)v;
    } else if (idx < N_PREP) {
        int j = idx - 7680;
        float v;
        if (j < 32) {                       // combined gate biases
            int c = j & 7, sel = j >> 3;
            v = (sel==0) ? b_i2h[c]    + b_ret[c]
              : (sel==1) ? b_i2h[8+c]  + b_ret[8+c]
              : (sel==2) ? b_i2h[16+c] : b_ret[16+c];
        } else if (j < 128) v = w_out[j-32];
        else if (j < 140)   v = b_out[j-128];
        else                v = b_in[j-140];   // conv_in bias (epilogue add)
        fw[j] = v;
    }
}

__device__ __forceinline__ void pack24(_Float16* dst, const float* v)
{
    union { h2f h2[12]; v8h h8[3]; } u;
#pragma unroll
    for (int k = 0; k < 12; ++k)
        u.h2[k] = __builtin_amdgcn_cvt_pkrtz(v[2 * k], v[2 * k + 1]);
#pragma unroll
    for (int k = 0; k < 3; ++k) *(v8h*)&dst[8 * k] = u.h8[k];
}

// conv_in .. gates for one tile (pool-local). No trailing barrier.
__device__ __forceinline__ void tile_front(char* pool, const _Float16* wh,
    const float* fw, int lane, int wave, int quad, int col,
    int ty0, int tx0)
{
    _Float16* s_in = (_Float16*)pool;
    _Float16* s_x  = (_Float16*)pool;
    float*    s_hc = (float*)(pool + 9792);

    // ---- conv_in: 39 M-tiles over 8 waves (5/wave), 9 MFMA each ----
    int toffA[3];
#pragma unroll
    for (int s = 0; s < 3; ++s) {
        int t = s * 4 + quad;               // tap carried by this quad
        toffA[s] = (t < 9) ? ((t / 3) * PCOLS + (t % 3)) * SPITCH : 0;
    }
    int pbase[5];
#pragma unroll
    for (int t = 0; t < 5; ++t) {
        int p = (wave + 8 * t) * 16 + col; if (p > SXN - 1) p = SXN - 1;
        pbase[t] = ((p / SXW) * PCOLS + (p % SXW)) * SPITCH;
    }
    v4f accA[5];
#pragma unroll
    for (int t = 0; t < 5; ++t) accA[t] = (v4f){0.f, 0.f, 0.f, 0.f};
#pragma unroll
    for (int s = 0; s < 3; ++s) {
        v8h bg[3];                          // B-frags for this K-step only
#pragma unroll
        for (int g = 0; g < 3; ++g)
            bg[g] = *(const v8h*)&wh[((s * 3 + g) * 64 + lane) * 8];
#pragma unroll
        for (int t = 0; t < 5; ++t) {
            if (wave + 8 * t < 39) {
                int ab = pbase[t] + toffA[s];
#pragma unroll
                for (int g = 0; g < 3; ++g) {
                    v8h a = *(const v8h*)&s_in[ab + g * 8];
                    accA[t] = __builtin_amdgcn_mfma_f32_16x16x32_f16(a, bg[g], accA[t], 0, 0, 0);
                }
            }
        }
    }
    __syncthreads();   // all s_in reads complete before s_x overwrites pool head

    // ---- write s_x (x zero-padded outside the image; + b_in inside) ----
    const float binv = fw[140 + (col & 7)];
    if (col < 8) {
#pragma unroll
        for (int t = 0; t < 5; ++t) {
            int mt = wave + 8 * t;
            if (mt < 39) {
#pragma unroll
                for (int r = 0; r < 4; ++r) {
                    int pa = mt * 16 + quad * 4 + r;
                    int py = pa / SXW, px = pa - SXW * py;
                    bool ok = ((unsigned)(ty0 + py - 1) < HW) &&
                              ((unsigned)(tx0 + px - 1) < HW);
                    if (pa < SXN)
                        s_x[pa * 8 + col] = (_Float16)(ok ? accA[t][r] + binv : 0.f);
                }
            }
        }
    }
    __syncthreads();

    // ---- i2h: 32 M-tiles over 8 waves (4/wave), 3 K-steps, 2 N-tiles ----
    int toff2[3];
#pragma unroll
    for (int s = 0; s < 3; ++s) {
        int t = s * 4 + quad;
        toff2[s] = (t < 9) ? ((t / 3) * SXW + (t % 3)) * 8 : 0;
    }
    int abase2[4];
#pragma unroll
    for (int t = 0; t < 4; ++t) {
        int q = (wave + 8 * t) * 16 + col;  // 0..511
        abase2[t] = ((q >> 5) * SXW + (q & 31)) * 8;
    }
    v4f acc0[4], acc1[4];
#pragma unroll
    for (int t = 0; t < 4; ++t) {
        acc0[t] = (v4f){0.f, 0.f, 0.f, 0.f};
        acc1[t] = (v4f){0.f, 0.f, 0.f, 0.f};
    }
#pragma unroll
    for (int s = 0; s < 3; ++s) {
        v8h b0 = *(const v8h*)&wh[WB_HOFF + ((s * 2 + 0) * 64 + lane) * 8];
        v8h b1 = *(const v8h*)&wh[WB_HOFF + ((s * 2 + 1) * 64 + lane) * 8];
#pragma unroll
        for (int t = 0; t < 4; ++t) {
            v8h a = *(const v8h*)&s_x[abase2[t] + toff2[s]];
            acc0[t] = __builtin_amdgcn_mfma_f32_16x16x32_f16(a, b0, acc0[t], 0, 0, 0);
            acc1[t] = __builtin_amdgcn_mfma_f32_16x16x32_f16(a, b1, acc1[t], 0, 0, 0);
        }
    }

    // ---- gates from C-frags (write s_hc — disjoint from s_x, no barrier) ----
    const int c7 = lane & 7;
    const float g0v = fw[c7], g1v = fw[8 + c7], g2v = fw[16 + c7], g3v = fw[24 + c7];
#pragma unroll
    for (int t = 0; t < 4; ++t) {
        int mt = wave + 8 * t;
#pragma unroll
        for (int r = 0; r < 4; ++r) {
            float iu = __shfl_xor(acc0[t][r], 8, 64);
            if (col < 8) {
                float rr = 1.f / (1.f + __expf(-(acc0[t][r] + g0v)));
                float uu = 1.f / (1.f + __expf(-(iu + g1v)));
                float mm = acc1[t][r] + g2v + rr * g3v;
                mm = (mm >= 0.f) ? mm : 0.2f * mm;
                s_hc[(mt * 16 + quad * 4 + r) * 9 + c7] = (1.f - uu) * mm;
            }
        }
    }
}

// barrier + conv_out for one tile.
__device__ __forceinline__ void tile_back(char* pool, const float* fw,
    int tid, int b, int ty0, int tx0, float* __restrict__ out)
{
    __syncthreads();
    float* s_hc = (float*)(pool + 9792);
    float h[8];
#pragma unroll
    for (int c = 0; c < 8; ++c) h[c] = s_hc[tid * 9 + c];
    const float* wout = fw + 32;
    const float* bout = fw + 128;
    const int oy = tid >> 5, ox = tid & 31;
    float* op = out + (((size_t)b * 12) << 14) + ((ty0 + oy) << 7) + (tx0 + ox);
#pragma unroll
    for (int t = 0; t < 12; ++t) {
        float o = bout[t];
#pragma unroll
        for (int c = 0; c < 8; ++c) o = fmaf(h[c], wout[t * 8 + c], o);
        op[(size_t)t << 14] = o;
    }
}

__global__ __launch_bounds__(512)
__attribute__((amdgpu_waves_per_eu(4, 4)))
void radar2_mfma(const float* __restrict__ radar,  // (32,12,128,128)
                 const float* __restrict__ pred,   // (32,12,128,128)
                 const void*  __restrict__ ws,
                 float* __restrict__ out)          // (32,12,128,128)
{
    // Two pools, ping-pong. Per pool: s_in [720][24] f16 = 34560 B;
    // s_x [612][8] f16 (9792 B) + s_hc [512][9] f32 (18432 B) alias it.
    __shared__ __align__(16) char pool[2 * POOLB];
    char* poolA = pool;
    char* poolB = pool + POOLB;

    const _Float16* wh = (const _Float16*)ws;
    const float* fw = (const float*)((const char*)ws + FLT_OFF);

    const int tid  = threadIdx.x;
    const int lane = tid & 63;
    const int wave = tid >> 6;          // 0..7
    const int quad = lane >> 4;
    const int col  = lane & 15;

    // XCD swizzle: id&7 = XCD; per XCD 64 blocks = 4 whole images.
    const int id   = blockIdx.x;        // 0..511
    const int b    = (id & 7) * 4 + (id >> 7);
    const int bi   = (id >> 3) & 15;    // block-in-image: 8 ty x 2 tx-pairs
    const int ty0  = (bi >> 1) << 4;
    const int tx0A = (bi & 1) << 6;     // 0 or 64
    const int tx0B = tx0A + 32;

    // ---- staging geometry (shared by both tiles; gx differs by 32) ----
    const float* rb = radar + (((size_t)b * 12) << 14);
    const float* pb = pred  + (((size_t)b * 12) << 14);

    const int r0 = tid, r1 = tid + 512;
    const int ly0 = r0 / PCOLS, lx0 = r0 - PCOLS * ly0;
    const int gy0 = ty0 + ly0 - 2;
    const bool has1 = (r1 < NPOS);      // tid < 208
    const int ly1 = r1 / PCOLS, lx1 = r1 - PCOLS * ly1;
    const int gy1 = ty0 + ly1 - 2;

    const int gxA0 = tx0A + lx0 - 2, gxA1 = tx0A + lx1 - 2;
    const int gxB0 = tx0B + lx0 - 2, gxB1 = tx0B + lx1 - 2;

    const bool inA0 = ((unsigned)gy0 < HW) & ((unsigned)gxA0 < HW);
    const bool inA1 = has1 & ((unsigned)gy1 < HW) & ((unsigned)gxA1 < HW);
    const bool inB0 = ((unsigned)gy0 < HW) & ((unsigned)gxB0 < HW);
    const bool inB1 = has1 & ((unsigned)gy1 < HW) & ((unsigned)gxB1 < HW);
    const int offA0 = (gy0 << 7) + gxA0, offA1 = (gy1 << 7) + gxA1;
    const int offB0 = (gy0 << 7) + gxB0, offB1 = (gy1 << 7) + gxB1;

    // ---- stage tile A ----
    {
        float va[24], vb[24];
#pragma unroll
        for (int c = 0; c < 12; ++c) {
            va[c]      = inA0 ? rb[((size_t)c << 14) + offA0] : 0.f;
            va[12 + c] = inA0 ? pb[((size_t)c << 14) + offA0] : 0.f;
        }
#pragma unroll
        for (int c = 0; c < 12; ++c) {
            vb[c]      = inA1 ? rb[((size_t)c << 14) + offA1] : 0.f;
            vb[12 + c] = inA1 ? pb[((size_t)c << 14) + offA1] : 0.f;
        }
        pack24(&((_Float16*)poolA)[r0 * SPITCH], va);
        if (has1) pack24(&((_Float16*)poolA)[r1 * SPITCH], vb);
    }
    __syncthreads();

    // ---- issue tile-B loads now; consumed after A's gates (~15us later) ----
    float vaB[24], vbB[24];
#pragma unroll
    for (int c = 0; c < 12; ++c) {
        vaB[c]      = inB0 ? rb[((size_t)c << 14) + offB0] : 0.f;
        vaB[12 + c] = inB0 ? pb[((size_t)c << 14) + offB0] : 0.f;
    }
#pragma unroll
    for (int c = 0; c < 12; ++c) {
        vbB[c]      = inB1 ? rb[((size_t)c << 14) + offB1] : 0.f;
        vbB[12 + c] = inB1 ? pb[((size_t)c << 14) + offB1] : 0.f;
    }

    // ---- tile A compute (conv_in..gates), then stage B, then A conv_out ----
    tile_front(poolA, wh, fw, lane, wave, quad, col, ty0, tx0A);

    pack24(&((_Float16*)poolB)[r0 * SPITCH], vaB);
    if (has1) pack24(&((_Float16*)poolB)[r1 * SPITCH], vbB);

    tile_back(poolA, fw, tid, b, ty0, tx0A, out);   // leading sync orders poolB too

    // ---- tile B (conv_out-A overlaps conv_in-B: disjoint pools) ----
    tile_front(poolB, wh, fw, lane, wave, quad, col, ty0, tx0B);
    tile_back(poolB, fw, tid, b, ty0, tx0B, out);
}

extern "C" void kernel_launch(void* const* d_in, const int* in_sizes, int n_in,
                              void* d_out, int out_size, void* d_ws, size_t ws_size,
                              hipStream_t stream) {
    (void)in_sizes; (void)n_in; (void)ws_size; (void)out_size;
    const float* radar = (const float*)d_in[0];
    const float* pred  = (const float*)d_in[1];
    const float* w_in  = (const float*)d_in[2];
    const float* b_in  = (const float*)d_in[3];
    const float* w_i2h = (const float*)d_in[4];
    const float* b_i2h = (const float*)d_in[5];
    // d_in[6..12] (flow branch, w_ret) are dead: h0 == 0.
    const float* b_ret = (const float*)d_in[13];
    const float* w_out = (const float*)d_in[14];
    const float* b_out = (const float*)d_in[15];

    prep<<<(N_PREP + 255) / 256, 256, 0, stream>>>(w_in, b_in, w_i2h, b_i2h,
                                                   b_ret, w_out, b_out, d_ws);

    radar2_mfma<<<dim3(512), dim3(512), 0, stream>>>(radar, pred, d_ws, (float*)d_out);
}

// Round 10
// 145.167 us; speedup vs baseline: 1.0622x; 1.0622x over previous
//
#include <hip/hip_runtime.h>
#include <hip/hip_bf16.h>

// RadarSecondStageGenerator — MFMA fp16, round 18 (resubmit; round-9 bench
// was a GPU-acquisition timeout, kernel never ran): 2-tile pipeline with an
// LDS prefetch buffer (spill-proof). r16/r17 proved the compiler will not
// hold 48 prefetch floats in registers (VGPR pinned at 64, ~50MB scratch
// round-trip). This round keeps the pipeline but stages tile B in two
// TRANSIENT half-passes straight into poolB:
//   phase1 (12 radar ch -> f16 -> poolB lo-halfs) issued right after A's
//     staging barrier: HBM latency hides under ALL of A's compute;
//   phase2 (12 pred ch) loads issued after A's gates, in flight through
//     tile_back(A) (24 transient f32 + ~25-reg conv_out fits 64 VGPR),
//     cvt+write poolB hi-halfs, one barrier, then tile B.
// No register state crosses tile_front -> cannot spill by construction.
// tile_front/tile_back byte-identical to r12/r16 (correctness-proven).
// LDS 2x34560 = 69KB -> 2 blocks/CU; grid 512 x 512 thr.
//
// h0 == 0 ⇒ flow/warp/w_ret branch dead; network = conv3x3(24->8) ->
// conv3x3(8->24) -> GRU gates (h2h == b_ret) -> conv1x1(8->12).
// conv_in im2col: M = 612 x-halo px (39 tiles), N = 8, K-step = 4 taps x 8 ch.
// i2h: M = 512 px (32 tiles), N = 24 (2 N-tiles), K = 12 taps x 8 ch (3 steps).
// Fragment layouts (HW-verified): A[m=lane&15][k=quad*8+j], C[row=quad*4+reg][col=lane&15].

typedef __fp16   h2f __attribute__((ext_vector_type(2)));   // cvt_pkrtz return type
typedef _Float16 v4h __attribute__((ext_vector_type(4)));
typedef _Float16 v8h __attribute__((ext_vector_type(8)));
typedef float    v4f __attribute__((ext_vector_type(4)));

#define HW 128
#define SPITCH 24        // halfs per staged position: 48 B, 16B-aligned, bank-clean
#define PCOLS 36         // staged patch: 36 cols x 20 rows
#define NPOS  720
#define SXW   34         // s_x grid 34 x 18
#define SXN   612
#define POOLB 34560      // one staging pool (bytes)

#define WB_HOFF 4608     // half-index of i2h B-frags in ws
#define FLT_OFF 16384    // byte offset of float params in ws
#define N_PREP  7828     // 4608 + 3072 halfs, then 148 floats

__global__ __launch_bounds__(256)
void prep(const float* __restrict__ w_in,  const float* __restrict__ b_in,
          const float* __restrict__ w_i2h, const float* __restrict__ b_i2h,
          const float* __restrict__ b_ret, const float* __restrict__ w_out,
          const float* __restrict__ b_out, void* __restrict__ ws)
{
    int idx = blockIdx.x * 256 + threadIdx.x;
    _Float16* wh = (_Float16*)ws;
    float* fw = (float*)((char*)ws + FLT_OFF);
    if (idx < 4608) {                       // conv_in B-frags [s3][g3][lane64][j8]
        int j = idx & 7, r = idx >> 3;
        int lane = r & 63, sg = r >> 6;     // sg = s*3 + g
        int g = sg % 3, s = sg / 3;
        int quad = lane >> 4, n = lane & 15;
        int tap = s * 4 + quad;             // 0..11 (9..11 zero pad)
        float v = (n < 8 && tap < 9) ? w_in[n*216 + (g*8 + j)*9 + tap] : 0.f;
        wh[idx] = (_Float16)v;
    } else if (idx < 7680) {                // i2h B-frags [s3][nt2][lane64][j8]
        int i2 = idx - 4608;
        int j = i2 & 7, r = i2 >> 3;
        int lane = r & 63; r >>= 6;
        int nt = r & 1, s = r >> 1;
        int quad = lane >> 4, n = lane & 15;
        int kk = s * 32 + quad * 8 + j;     // K: tap-major, 8 ch per tap
        int t = kk >> 3, m = kk & 7;        // tap 0..11 (9..11 pad)
        int o = nt * 16 + n;
        float v = (t < 9 && o < 24) ? w_i2h[o*72 + m*9 + t] : 0.f;
        wh[WB_HOFF + i2] = (_Float16)v;
    } else if (idx < N_PREP) {
        int j = idx - 7680;
        float v;
        if (j < 32) {                       // combined gate biases
            int c = j & 7, sel = j >> 3;
            v = (sel==0) ? b_i2h[c]    + b_ret[c]
              : (sel==1) ? b_i2h[8+c]  + b_ret[8+c]
              : (sel==2) ? b_i2h[16+c] : b_ret[16+c];
        } else if (j < 128) v = w_out[j-32];
        else if (j < 140)   v = b_out[j-128];
        else                v = b_in[j-140];   // conv_in bias (epilogue add)
        fw[j] = v;
    }
}

__device__ __forceinline__ void pack24(_Float16* dst, const float* v)
{
    union { h2f h2[12]; v8h h8[3]; } u;
#pragma unroll
    for (int k = 0; k < 12; ++k)
        u.h2[k] = __builtin_amdgcn_cvt_pkrtz(v[2 * k], v[2 * k + 1]);
#pragma unroll
    for (int k = 0; k < 3; ++k) *(v8h*)&dst[8 * k] = u.h8[k];
}

// halfs 0..11 of a position: b128 @0 + b64 @8h
__device__ __forceinline__ void pack12_lo(_Float16* dst, const float* v)
{
    union { h2f h2[4]; v8h h8; } u;
    union { h2f h2[2]; v4h h4; } w;
#pragma unroll
    for (int k = 0; k < 4; ++k)
        u.h2[k] = __builtin_amdgcn_cvt_pkrtz(v[2*k], v[2*k+1]);
    w.h2[0] = __builtin_amdgcn_cvt_pkrtz(v[8], v[9]);
    w.h2[1] = __builtin_amdgcn_cvt_pkrtz(v[10], v[11]);
    *(v8h*)&dst[0] = u.h8;
    *(v4h*)&dst[8] = w.h4;
}

// halfs 12..23 of a position: b64 @12h + b128 @16h
__device__ __forceinline__ void pack12_hi(_Float16* dst, const float* v)
{
    union { h2f h2[2]; v4h h4; } w;
    union { h2f h2[4]; v8h h8; } u;
    w.h2[0] = __builtin_amdgcn_cvt_pkrtz(v[0], v[1]);
    w.h2[1] = __builtin_amdgcn_cvt_pkrtz(v[2], v[3]);
#pragma unroll
    for (int k = 0; k < 4; ++k)
        u.h2[k] = __builtin_amdgcn_cvt_pkrtz(v[4 + 2*k], v[5 + 2*k]);
    *(v4h*)&dst[12] = w.h4;
    *(v8h*)&dst[16] = u.h8;
}

// conv_in .. gates for one tile (pool-local). No trailing barrier.
__device__ __forceinline__ void tile_front(char* pool, const _Float16* wh,
    const float* fw, int lane, int wave, int quad, int col,
    int ty0, int tx0)
{
    _Float16* s_in = (_Float16*)pool;
    _Float16* s_x  = (_Float16*)pool;
    float*    s_hc = (float*)(pool + 9792);

    // ---- conv_in: 39 M-tiles over 8 waves (5/wave), 9 MFMA each ----
    int toffA[3];
#pragma unroll
    for (int s = 0; s < 3; ++s) {
        int t = s * 4 + quad;               // tap carried by this quad
        toffA[s] = (t < 9) ? ((t / 3) * PCOLS + (t % 3)) * SPITCH : 0;
    }
    int pbase[5];
#pragma unroll
    for (int t = 0; t < 5; ++t) {
        int p = (wave + 8 * t) * 16 + col; if (p > SXN - 1) p = SXN - 1;
        pbase[t] = ((p / SXW) * PCOLS + (p % SXW)) * SPITCH;
    }
    v4f accA[5];
#pragma unroll
    for (int t = 0; t < 5; ++t) accA[t] = (v4f){0.f, 0.f, 0.f, 0.f};
#pragma unroll
    for (int s = 0; s < 3; ++s) {
        v8h bg[3];                          // B-frags for this K-step only
#pragma unroll
        for (int g = 0; g < 3; ++g)
            bg[g] = *(const v8h*)&wh[((s * 3 + g) * 64 + lane) * 8];
#pragma unroll
        for (int t = 0; t < 5; ++t) {
            if (wave + 8 * t < 39) {
                int ab = pbase[t] + toffA[s];
#pragma unroll
                for (int g = 0; g < 3; ++g) {
                    v8h a = *(const v8h*)&s_in[ab + g * 8];
                    accA[t] = __builtin_amdgcn_mfma_f32_16x16x32_f16(a, bg[g], accA[t], 0, 0, 0);
                }
            }
        }
    }
    __syncthreads();   // all s_in reads complete before s_x overwrites pool head

    // ---- write s_x (x zero-padded outside the image; + b_in inside) ----
    const float binv = fw[140 + (col & 7)];
    if (col < 8) {
#pragma unroll
        for (int t = 0; t < 5; ++t) {
            int mt = wave + 8 * t;
            if (mt < 39) {
#pragma unroll
                for (int r = 0; r < 4; ++r) {
                    int pa = mt * 16 + quad * 4 + r;
                    int py = pa / SXW, px = pa - SXW * py;
                    bool ok = ((unsigned)(ty0 + py - 1) < HW) &&
                              ((unsigned)(tx0 + px - 1) < HW);
                    if (pa < SXN)
                        s_x[pa * 8 + col] = (_Float16)(ok ? accA[t][r] + binv : 0.f);
                }
            }
        }
    }
    __syncthreads();

    // ---- i2h: 32 M-tiles over 8 waves (4/wave), 3 K-steps, 2 N-tiles ----
    int toff2[3];
#pragma unroll
    for (int s = 0; s < 3; ++s) {
        int t = s * 4 + quad;
        toff2[s] = (t < 9) ? ((t / 3) * SXW + (t % 3)) * 8 : 0;
    }
    int abase2[4];
#pragma unroll
    for (int t = 0; t < 4; ++t) {
        int q = (wave + 8 * t) * 16 + col;  // 0..511
        abase2[t] = ((q >> 5) * SXW + (q & 31)) * 8;
    }
    v4f acc0[4], acc1[4];
#pragma unroll
    for (int t = 0; t < 4; ++t) {
        acc0[t] = (v4f){0.f, 0.f, 0.f, 0.f};
        acc1[t] = (v4f){0.f, 0.f, 0.f, 0.f};
    }
#pragma unroll
    for (int s = 0; s < 3; ++s) {
        v8h b0 = *(const v8h*)&wh[WB_HOFF + ((s * 2 + 0) * 64 + lane) * 8];
        v8h b1 = *(const v8h*)&wh[WB_HOFF + ((s * 2 + 1) * 64 + lane) * 8];
#pragma unroll
        for (int t = 0; t < 4; ++t) {
            v8h a = *(const v8h*)&s_x[abase2[t] + toff2[s]];
            acc0[t] = __builtin_amdgcn_mfma_f32_16x16x32_f16(a, b0, acc0[t], 0, 0, 0);
            acc1[t] = __builtin_amdgcn_mfma_f32_16x16x32_f16(a, b1, acc1[t], 0, 0, 0);
        }
    }

    // ---- gates from C-frags (write s_hc — disjoint from s_x, no barrier) ----
    const int c7 = lane & 7;
    const float g0v = fw[c7], g1v = fw[8 + c7], g2v = fw[16 + c7], g3v = fw[24 + c7];
#pragma unroll
    for (int t = 0; t < 4; ++t) {
        int mt = wave + 8 * t;
#pragma unroll
        for (int r = 0; r < 4; ++r) {
            float iu = __shfl_xor(acc0[t][r], 8, 64);
            if (col < 8) {
                float rr = 1.f / (1.f + __expf(-(acc0[t][r] + g0v)));
                float uu = 1.f / (1.f + __expf(-(iu + g1v)));
                float mm = acc1[t][r] + g2v + rr * g3v;
                mm = (mm >= 0.f) ? mm : 0.2f * mm;
                s_hc[(mt * 16 + quad * 4 + r) * 9 + c7] = (1.f - uu) * mm;
            }
        }
    }
}

// barrier + conv_out for one tile.
__device__ __forceinline__ void tile_back(char* pool, const float* fw,
    int tid, int b, int ty0, int tx0, float* __restrict__ out)
{
    __syncthreads();
    float* s_hc = (float*)(pool + 9792);
    float h[8];
#pragma unroll
    for (int c = 0; c < 8; ++c) h[c] = s_hc[tid * 9 + c];
    const float* wout = fw + 32;
    const float* bout = fw + 128;
    const int oy = tid >> 5, ox = tid & 31;
    float* op = out + (((size_t)b * 12) << 14) + ((ty0 + oy) << 7) + (tx0 + ox);
#pragma unroll
    for (int t = 0; t < 12; ++t) {
        float o = bout[t];
#pragma unroll
        for (int c = 0; c < 8; ++c) o = fmaf(h[c], wout[t * 8 + c], o);
        op[(size_t)t << 14] = o;
    }
}

__global__ __launch_bounds__(512, 4)
void radar2_mfma(const float* __restrict__ radar,  // (32,12,128,128)
                 const float* __restrict__ pred,   // (32,12,128,128)
                 const void*  __restrict__ ws,
                 float* __restrict__ out)          // (32,12,128,128)
{
    // Two pools. Per pool: s_in [720][24] f16 = 34560 B;
    // s_x [612][8] f16 (9792 B) + s_hc [512][9] f32 (18432 B) alias it.
    __shared__ __align__(16) char pool[2 * POOLB];
    char* poolA = pool;
    char* poolB = pool + POOLB;
    _Float16* pBh = (_Float16*)poolB;

    const _Float16* wh = (const _Float16*)ws;
    const float* fw = (const float*)((const char*)ws + FLT_OFF);

    const int tid  = threadIdx.x;
    const int lane = tid & 63;
    const int wave = tid >> 6;          // 0..7
    const int quad = lane >> 4;
    const int col  = lane & 15;

    // XCD swizzle: id&7 = XCD; per XCD 64 blocks = 4 whole images.
    const int id   = blockIdx.x;        // 0..511
    const int b    = (id & 7) * 4 + (id >> 7);
    const int bi   = (id >> 3) & 15;    // block-in-image: 8 ty x 2 tx-pairs
    const int ty0  = (bi >> 1) << 4;
    const int tx0A = (bi & 1) << 6;     // 0 or 64
    const int tx0B = tx0A + 32;

    // ---- staging geometry (shared by both tiles; gx differs by 32) ----
    const float* rb = radar + (((size_t)b * 12) << 14);
    const float* pb = pred  + (((size_t)b * 12) << 14);

    const int r0 = tid, r1 = tid + 512;
    const int ly0 = r0 / PCOLS, lx0 = r0 - PCOLS * ly0;
    const int gy0 = ty0 + ly0 - 2;
    const bool has1 = (r1 < NPOS);      // tid < 208
    const int ly1 = r1 / PCOLS, lx1 = r1 - PCOLS * ly1;
    const int gy1 = ty0 + ly1 - 2;

    const int gxA0 = tx0A + lx0 - 2, gxA1 = tx0A + lx1 - 2;
    const int gxB0 = tx0B + lx0 - 2, gxB1 = tx0B + lx1 - 2;

    const bool inA0 = ((unsigned)gy0 < HW) & ((unsigned)gxA0 < HW);
    const bool inA1 = has1 & ((unsigned)gy1 < HW) & ((unsigned)gxA1 < HW);
    const bool inB0 = ((unsigned)gy0 < HW) & ((unsigned)gxB0 < HW);
    const bool inB1 = has1 & ((unsigned)gy1 < HW) & ((unsigned)gxB1 < HW);
    const int offA0 = (gy0 << 7) + gxA0, offA1 = (gy1 << 7) + gxA1;
    const int offB0 = (gy0 << 7) + gxB0, offB1 = (gy1 << 7) + gxB1;

    // ---- stage tile A (full 24 ch) ----
    {
        float va[24], vb[24];
#pragma unroll
        for (int c = 0; c < 12; ++c) {
            va[c]      = inA0 ? rb[((size_t)c << 14) + offA0] : 0.f;
            va[12 + c] = inA0 ? pb[((size_t)c << 14) + offA0] : 0.f;
        }
#pragma unroll
        for (int c = 0; c < 12; ++c) {
            vb[c]      = inA1 ? rb[((size_t)c << 14) + offA1] : 0.f;
            vb[12 + c] = inA1 ? pb[((size_t)c << 14) + offA1] : 0.f;
        }
        pack24(&((_Float16*)poolA)[r0 * SPITCH], va);
        if (has1) pack24(&((_Float16*)poolA)[r1 * SPITCH], vb);
    }
    __syncthreads();

    // ---- phase1: tile-B radar channels -> poolB lo-halfs (transient) ----
    {
        float f0[12], f1[12];
#pragma unroll
        for (int c = 0; c < 12; ++c) f0[c] = inB0 ? rb[((size_t)c << 14) + offB0] : 0.f;
#pragma unroll
        for (int c = 0; c < 12; ++c) f1[c] = inB1 ? rb[((size_t)c << 14) + offB1] : 0.f;
        pack12_lo(&pBh[r0 * SPITCH], f0);
        if (has1) pack12_lo(&pBh[r1 * SPITCH], f1);
    }

    // ---- tile A compute (conv_in..gates); phase1 latency hides here ----
    tile_front(poolA, wh, fw, lane, wave, quad, col, ty0, tx0A);

    // ---- phase2 loads: tile-B pred channels (in flight through conv_out A) ----
    float g0[12], g1[12];
#pragma unroll
    for (int c = 0; c < 12; ++c) g0[c] = inB0 ? pb[((size_t)c << 14) + offB0] : 0.f;
#pragma unroll
    for (int c = 0; c < 12; ++c) g1[c] = inB1 ? pb[((size_t)c << 14) + offB1] : 0.f;

    tile_back(poolA, fw, tid, b, ty0, tx0A, out);   // barrier + conv_out A

    // ---- phase2 finish: write poolB hi-halfs ----
    pack12_hi(&pBh[r0 * SPITCH], g0);
    if (has1) pack12_hi(&pBh[r1 * SPITCH], g1);
    __syncthreads();    // poolB fully staged

    // ---- tile B ----
    tile_front(poolB, wh, fw, lane, wave, quad, col, ty0, tx0B);
    tile_back(poolB, fw, tid, b, ty0, tx0B, out);
}

extern "C" void kernel_launch(void* const* d_in, const int* in_sizes, int n_in,
                              void* d_out, int out_size, void* d_ws, size_t ws_size,
                              hipStream_t stream) {
    (void)in_sizes; (void)n_in; (void)ws_size; (void)out_size;
    const float* radar = (const float*)d_in[0];
    const float* pred  = (const float*)d_in[1];
    const float* w_in  = (const float*)d_in[2];
    const float* b_in  = (const float*)d_in[3];
    const float* w_i2h = (const float*)d_in[4];
    const float* b_i2h = (const float*)d_in[5];
    // d_in[6..12] (flow branch, w_ret) are dead: h0 == 0.
    const float* b_ret = (const float*)d_in[13];
    const float* w_out = (const float*)d_in[14];
    const float* b_out = (const float*)d_in[15];

    prep<<<(N_PREP + 255) / 256, 256, 0, stream>>>(w_in, b_in, w_i2h, b_i2h,
                                                   b_ret, w_out, b_out, d_ws);

    radar2_mfma<<<dim3(512), dim3(512), 0, stream>>>(radar, pred, d_ws, (float*)d_out);
}